// Round 12
// baseline (770.219 us; speedup 1.0000x reference)
//
#include <hip/hip_runtime.h>

#define IGNORE_INDEX (-100)

constexpr int N_ROWS = 2048;
constexpr int D_DIM  = 1024;
constexpr int V_DIM  = 131072;
constexpr int BM = 256, BN = 128, BK = 128;
constexpr int ROW_TILES = N_ROWS / BM;        // 8
constexpr int COL_TILES = V_DIM / BN;         // 1024
constexpr int K_TILES = D_DIM / BK;           // 8
constexpr int PPB = 4;                        // panels per block (1024/256)

typedef __attribute__((ext_vector_type(4))) float f32x4;
typedef __attribute__((ext_vector_type(4))) int   i32x4;
typedef __attribute__((ext_vector_type(8))) int   i32x8;

// Uniform E8M0 scales: hidden at prescale 1 (2^0=127), weight at prescale 64
// (2^-6=121). Product 2^0 * 2^-6 * 64 = 1. Uniform bytes -> layout-proof.
#define SCL_A 0x7F7F7F7Fu
#define SCL_B 0x79797979u

// ---------------- f32 -> fp4 e2m1 (software RNE to grid) --------------------
__device__ __forceinline__ unsigned int f2fp4(float f) {
  const float a = fabsf(f);
  unsigned int c = (unsigned)(a >= 0.25f) + (unsigned)(a >= 0.75f) +
                   (unsigned)(a >= 1.25f) + (unsigned)(a >= 1.75f) +
                   (unsigned)(a >= 2.5f)  + (unsigned)(a >= 3.5f) +
                   (unsigned)(a >= 5.0f);
  return c | ((__float_as_uint(f) >> 31) << 3);
}

// hidden f32 -> fp4 (row-major, low nibble first), 32 elems/thread
__global__ __launch_bounds__(256)
void cvt_fp4(const float* __restrict__ src, unsigned char* __restrict__ dst) {
  const size_t i = ((size_t)blockIdx.x * 256 + (size_t)threadIdx.x) * 32;
  i32x4 o;
#pragma unroll
  for (int q = 0; q < 4; ++q) {
    unsigned int wrd = 0;
#pragma unroll
    for (int e = 0; e < 8; e += 4) {
      const float4 f = *(const float4*)&src[i + q * 8 + e];
      wrd |= f2fp4(f.x) << ((e + 0) * 4);
      wrd |= f2fp4(f.y) << ((e + 1) * 4);
      wrd |= f2fp4(f.z) << ((e + 2) * 4);
      wrd |= f2fp4(f.w) << ((e + 3) * 4);
    }
    o[q] = (int)wrd;
  }
  *(i32x4*)&dst[i / 2] = o;
}

// --------- fused weight-convert + MX-fp4 GEMM + partial row exp-sum ---------
// Persistent: 256 blocks (1/CU), each owns 4 col-panels (BN=128). Panel p+1's
// f32->fp4 conversion is interleaved into panel p's 64 k-steps (1 float4 load
// + pack + ds_write_b16 per thread per step). Panels double-buffered in LDS;
// B needs NO staging DMA. A staged via round-8/10's proven gload_lds path.
#define BAR() __builtin_amdgcn_s_barrier()
#define SP1() __builtin_amdgcn_s_setprio(1)
#define SP0() __builtin_amdgcn_s_setprio(0)
#define SCHB() __builtin_amdgcn_sched_barrier(0)
#define VM0() asm volatile("s_waitcnt vmcnt(0)" ::: "memory")

// stage one 256x128-elem fp4 A-tile (16 KB): 2 x global_load_lds(16B)/thread
#define STAGE_A(rtoff, kt, ab)                                                 \
  {                                                                            \
    _Pragma("unroll") for (int j2_ = 0; j2_ < 2; ++j2_) {                      \
      const char* g_ = hab + (rtoff) + (size_t)j2_ * 65536 + (size_t)(kt) * 64;\
      __builtin_amdgcn_global_load_lds(                                        \
          (const __attribute__((address_space(1))) unsigned int*)g_,           \
          (__attribute__((address_space(3))) unsigned int*)(smem + 131072 +    \
              (ab) * 16384 + j2_ * 8192 + (tid << 4)),                         \
          16, 0, 0);                                                           \
    }                                                                          \
  }

// read ONE frag (16 rows x K=128 fp4 = 16 B/lane); conflict-free (proven)
#define READ_FRAG(base, rowbase, dst)                                          \
  {                                                                            \
    const i32x4 d_ = *(const i32x4*)(smem + (base) +                           \
                                     ((rowbase) + l15) * 64 + gcol);           \
    dst = (i32x8){d_[0], d_[1], d_[2], d_[3], 0, 0, 0, 0};                     \
  }

__global__ __launch_bounds__(512, 1)
void lse_fused(const unsigned char* __restrict__ hf4,
               const float* __restrict__ weight,
               const float* __restrict__ bias,
               float* __restrict__ ps) {
  // PB0 @0 (64K) | PB1 @65536 (64K) | A0 @131072 (16K) | A1 @147456 (16K)
  __shared__ __align__(16) char smem[163840];

  const int tid = threadIdx.x;
  const int lane = tid & 63;
  const int wv = tid >> 6, wm = wv >> 1, wn = wv & 1;   // 4x2 waves, 64x64 out
  const int l15 = lane & 15, l16g = lane >> 4;
  const int gcol = (l16g ^ ((l15 >> 1) & 3)) << 4;      // frag-read swizzle

  // A staging source (round-8/10 proven involution)
  const int ra_ = tid >> 2;
  const int Ga_ = (tid & 3) ^ ((ra_ >> 1) & 3);
  const char* hab = (const char*)hf4 + (size_t)ra_ * 512 + Ga_ * 16;

  // cvt decomposition: 8 lanes cooperatively build each 16B granule
  const int sub = tid & 7, Gc = (tid >> 3) & 3, ktc = (tid >> 5) & 7;
  const int rhi = tid >> 8;
  const int cvsrc = ktc * 128 + Gc * 32 + sub * 4;      // f32 col offset

  f32x4 acc[4][4];
  const f32x4 zero = {0.f, 0.f, 0.f, 0.f};
  i32x8 ar[2], breg[4];

  // ---- prologue: convert panel 0 into PB0 ----
  {
    const int v00 = blockIdx.x * PPB * BN;
#pragma unroll 4
    for (int i = 0; i < 64; ++i) {
      const int rr = 2 * i + rhi;
      const float4 wx = *(const float4*)&weight[(size_t)(v00 + rr) * 1024 + cvsrc];
      const unsigned int b0 = f2fp4(wx.x * 64.f) | (f2fp4(wx.y * 64.f) << 4);
      const unsigned int b1 = f2fp4(wx.z * 64.f) | (f2fp4(wx.w * 64.f) << 4);
      *(unsigned short*)(smem + ktc * 8192 + rr * 64 + ((Gc ^ (i & 3)) << 4) +
                         sub * 2) = (unsigned short)(b0 | (b1 << 8));
    }
  }
  __syncthreads();

  int cur = 0;
  for (int p = 0; p < PPB; ++p) {
    const int colt = blockIdx.x * PPB + p;
    const int v0 = colt * BN;
    const int v0n = v0 + BN;                 // next panel rows (if any)
    const bool docvt = (p < PPB - 1);
    const int nxt = cur ^ 1;

    float bv[4];
#pragma unroll
    for (int q = 0; q < 4; ++q)
      bv[q] = bias[v0 + wn * 64 + q * 16 + l15];

    for (int rt = 0; rt < ROW_TILES; ++rt) {
      const size_t rtoff = (size_t)rt * 131072;  // 256 rows x 512 B
#pragma unroll
      for (int i = 0; i < 4; ++i)
#pragma unroll
        for (int j = 0; j < 4; ++j) acc[i][j] = zero;

      STAGE_A(rtoff, 0, 0);
#pragma unroll
      for (int kt = 0; kt < K_TILES; ++kt) {
        VM0();             // A(kt) DMA landed (issued a full step ago)
        BAR();             // visible to all waves; prev buf readers done
        SCHB();
        const int i = rt * 8 + kt;
        const int rr = 2 * i + rhi;
        float4 wx;
        if (docvt)         // issue panel-(p+1) piece load early (hides in step)
          wx = *(const float4*)&weight[(size_t)(v0n + rr) * 1024 + cvsrc];
        if (kt < K_TILES - 1) STAGE_A(rtoff, kt + 1, (kt + 1) & 1);
        SCHB();
        // B frags from resident panel (x4 reuse by A-frag stream)
#pragma unroll
        for (int q = 0; q < 4; ++q)
          READ_FRAG(cur * 65536 + kt * 8192, wn * 64 + q * 16, breg[q]);
        // stream 4 A-frags, 2-deep; 4 MFMAs per frag
        READ_FRAG(131072 + (kt & 1) * 16384, wm * 64, ar[0]);
#pragma unroll
        for (int f = 0; f < 4; ++f) {
          if (f < 3)
            READ_FRAG(131072 + (kt & 1) * 16384, wm * 64 + (f + 1) * 16,
                      ar[(f + 1) & 1]);
          SP1();
#pragma unroll
          for (int q = 0; q < 4; ++q)
            acc[f][q] = __builtin_amdgcn_mfma_scale_f32_16x16x128_f8f6f4(
                ar[f & 1], breg[q], acc[f][q], 4, 4, 0, SCL_A, 0, SCL_B);
          SP0();
        }
        if (docvt) {       // pack + write piece into PB[nxt]
          const unsigned int b0 = f2fp4(wx.x * 64.f) | (f2fp4(wx.y * 64.f) << 4);
          const unsigned int b1 = f2fp4(wx.z * 64.f) | (f2fp4(wx.w * 64.f) << 4);
          *(unsigned short*)(smem + nxt * 65536 + ktc * 8192 + rr * 64 +
                             ((Gc ^ (i & 3)) << 4) + sub * 2) =
              (unsigned short)(b0 | (b1 << 8));
        }
      }
      __syncthreads();
      // ---- epilogue: per-row sum(exp(x+bias)) over this panel's 128 cols ----
      float* red = (float*)(smem + 131072);  // [256][2] overlays A0
#pragma unroll
      for (int mi = 0; mi < 4; ++mi) {
#pragma unroll
        for (int r = 0; r < 4; ++r) {
          float se = __expf(acc[mi][0][r] + bv[0]) + __expf(acc[mi][1][r] + bv[1]) +
                     __expf(acc[mi][2][r] + bv[2]) + __expf(acc[mi][3][r] + bv[3]);
          se += __shfl_xor(se, 8); se += __shfl_xor(se, 4);
          se += __shfl_xor(se, 2); se += __shfl_xor(se, 1);
          if (l15 == 0)
            red[(wm * 64 + mi * 16 + l16g * 4 + r) * 2 + wn] = se;
        }
      }
      __syncthreads();
      if (tid < BM)
        ps[(size_t)(rt * BM + tid) * COL_TILES + colt] =
            red[tid * 2] + red[tid * 2 + 1];
      __syncthreads();     // red consumed; A0 region free for next rt
    }
    cur ^= 1;
  }
}

// ---------------- per-row finalize: sum partials -> lse, target logit, ce ----
__global__ __launch_bounds__(256)
void row_finalize(const float* __restrict__ ps,
                  const float* __restrict__ hidden, const float* __restrict__ weight,
                  const float* __restrict__ bias, const int* __restrict__ labels,
                  float* __restrict__ ce) {
  __shared__ float ss[4], sd[4];
  const int row = blockIdx.x;
  const int t = threadIdx.x, lane = t & 63, w = t >> 6;

  float s = 0.f;
#pragma unroll
  for (int i = 0; i < COL_TILES / 256; ++i)
    s += ps[(size_t)row * COL_TILES + t + i * 256];

  const int lbl = labels[row];
  const bool valid = (lbl != IGNORE_INDEX);
  float dot = 0.f;
  if (valid) {
    const float4 h4 = *(const float4*)&hidden[(size_t)row * D_DIM + t * 4];
    const float4 w4 = *(const float4*)&weight[(size_t)lbl * D_DIM + t * 4];
    dot = h4.x * w4.x + h4.y * w4.y + h4.z * w4.z + h4.w * w4.w;
  }
#pragma unroll
  for (int msk = 1; msk < 64; msk <<= 1) {
    s += __shfl_xor(s, msk);
    dot += __shfl_xor(dot, msk);
  }
  if (lane == 0) { ss[w] = s; sd[w] = dot; }
  __syncthreads();
  if (t == 0) {
    const float S = ss[0] + ss[1] + ss[2] + ss[3];
    const float d = sd[0] + sd[1] + sd[2] + sd[3];
    ce[row] = valid ? (logf(S + 1e-10f) - (d + bias[lbl])) : 0.f;
  }
}

// ---------------- final scalar reduce ----------------
__global__ __launch_bounds__(256)
void final_reduce(const float* __restrict__ ce, const int* __restrict__ labels,
                  float* __restrict__ out) {
  __shared__ float ssum[4];
  __shared__ int scnt[4];
  const int t = threadIdx.x, lane = t & 63, w = t >> 6;
  float sum = 0.f; int cnt = 0;
  for (int i = t; i < N_ROWS; i += 256) {
    sum += ce[i];
    cnt += (labels[i] != IGNORE_INDEX) ? 1 : 0;
  }
#pragma unroll
  for (int msk = 1; msk < 64; msk <<= 1) {
    sum += __shfl_xor(sum, msk);
    cnt += __shfl_xor(cnt, msk);
  }
  if (lane == 0) { ssum[w] = sum; scnt[w] = cnt; }
  __syncthreads();
  if (t == 0) {
    const float S = ssum[0] + ssum[1] + ssum[2] + ssum[3];
    const int C = scnt[0] + scnt[1] + scnt[2] + scnt[3];
    out[0] = S / fmaxf((float)C, 1.f);
  }
}

extern "C" void kernel_launch(void* const* d_in, const int* in_sizes, int n_in,
                              void* d_out, int out_size, void* d_ws, size_t ws_size,
                              hipStream_t stream) {
  const float* hidden = (const float*)d_in[0];
  const float* weight = (const float*)d_in[1];
  const float* bias   = (const float*)d_in[2];
  const int*   labels = (const int*)d_in[3];
  float* out = (float*)d_out;

  const size_t HF4_B = (size_t)N_ROWS * D_DIM / 2;         // 1 MB
  const size_t PS_B  = (size_t)N_ROWS * COL_TILES * 4;     // 8 MB
  const size_t CE_B  = (size_t)N_ROWS * 4;
  if (ws_size < HF4_B + PS_B + CE_B) return;

  char* ws = (char*)d_ws;
  unsigned char* hf4 = (unsigned char*)ws;
  float* ps = (float*)(ws + HF4_B);
  float* ce = (float*)(ws + HF4_B + PS_B);

  cvt_fp4<<<(int)((size_t)N_ROWS * D_DIM / 8192), 256, 0, stream>>>(hidden, hf4);
  lse_fused<<<256, 512, 0, stream>>>(hf4, weight, bias, ps);
  row_finalize<<<N_ROWS, 256, 0, stream>>>(ps, hidden, weight, bias, labels, ce);
  final_reduce<<<1, 256, 0, stream>>>(ce, labels, out);
}

// Round 13
// 474.121 us; speedup vs baseline: 1.6245x; 1.6245x over previous
//
#include <hip/hip_runtime.h>

#define IGNORE_INDEX (-100)

constexpr int N_ROWS = 2048;
constexpr int D_DIM  = 1024;
constexpr int V_DIM  = 131072;
constexpr int BM = 128, BN = 128, BK = 128;
constexpr int ROW_TILES = N_ROWS / BM;        // 16
constexpr int COL_TILES = V_DIM / BN;         // 1024
constexpr int NBLK = ROW_TILES * COL_TILES;   // 16384
constexpr int K_TILES = D_DIM / BK;           // 8

typedef __attribute__((ext_vector_type(4))) float f32x4;
typedef __attribute__((ext_vector_type(4))) int   i32x4;
typedef __attribute__((ext_vector_type(8))) int   i32x8;

// Uniform E8M0 scales: hidden at prescale 1 (2^0=127), weight at prescale 64
// (2^-6=121). Product 2^0 * 2^-6 * 64 = 1. Uniform bytes -> layout-proof.
#define SCL_A 0x7F7F7F7Fu
#define SCL_B 0x79797979u

// ---------------- f32 -> fp4 e2m1 (software RNE to grid), 32 elems/thread ----
__device__ __forceinline__ unsigned int f2fp4(float f) {
  const float a = fabsf(f);
  unsigned int c = (unsigned)(a >= 0.25f) + (unsigned)(a >= 0.75f) +
                   (unsigned)(a >= 1.25f) + (unsigned)(a >= 1.75f) +
                   (unsigned)(a >= 2.5f)  + (unsigned)(a >= 3.5f) +
                   (unsigned)(a >= 5.0f);
  return c | ((__float_as_uint(f) >> 31) << 3);
}

__global__ __launch_bounds__(256)
void cvt_fp4(const float* __restrict__ src, unsigned char* __restrict__ dst,
             float prescale) {
  const size_t i = ((size_t)blockIdx.x * 256 + (size_t)threadIdx.x) * 32;
  i32x4 o;
#pragma unroll
  for (int q = 0; q < 4; ++q) {        // 1 dword = 8 elems, low nibble first
    unsigned int wrd = 0;
#pragma unroll
    for (int e = 0; e < 8; e += 4) {
      const float4 f = *(const float4*)&src[i + q * 8 + e];
      wrd |= f2fp4(f.x * prescale) << ((e + 0) * 4);
      wrd |= f2fp4(f.y * prescale) << ((e + 1) * 4);
      wrd |= f2fp4(f.z * prescale) << ((e + 2) * 4);
      wrd |= f2fp4(f.w * prescale) << ((e + 3) * 4);
    }
    o[q] = (int)wrd;
  }
  *(i32x4*)&dst[i / 2] = o;
}

// ---------------- 128x128 MX-fp4 GEMM + partial row exp-sum ----------------
// 256-thr blocks (4 waves, 2x2 of 64x64 tiles; acc = 64 AGPR), 2 blocks/CU:
// the 2 waves on a SIMD belong to DIFFERENT blocks with independent barriers
// -> MFMA pipe stays fed across one block's VM/BAR stall (m114 overlap).
// Total reg demand ~150 of 256 -> no spill (r9/r11/r12 all died on this).
// Schedule = round-10's proven tribuf + counted VM4 + one barrier per K-tile.
#define BAR() __builtin_amdgcn_s_barrier()
#define SP1() __builtin_amdgcn_s_setprio(1)
#define SP0() __builtin_amdgcn_s_setprio(0)
#define SCHB() __builtin_amdgcn_sched_barrier(0)
#define VM4() asm volatile("s_waitcnt vmcnt(4)" ::: "memory")
#define VM0() asm volatile("s_waitcnt vmcnt(0)" ::: "memory")

// stage one 128x128-elem fp4 tile (8 KB): 2 x global_load_lds(16B)/thread.
// slot s = j*256+tid -> row j*64+(tid>>2), granule g = tid&3 (src holds G).
#define STAGE(gbase, ldsoff, kt, buf)                                          \
  {                                                                            \
    _Pragma("unroll") for (int j_ = 0; j_ < 2; ++j_) {                         \
      const char* g_ = (gbase) + (size_t)j_ * 32768 + (size_t)(kt) * 64;       \
      __builtin_amdgcn_global_load_lds(                                        \
          (const __attribute__((address_space(1))) unsigned int*)g_,           \
          (__attribute__((address_space(3))) unsigned int*)(smem + (ldsoff) +  \
              (buf) * 16384 + j_ * 4096 + (tid << 4)),                         \
          16, 0, 0);                                                           \
    }                                                                          \
  }

// read ONE frag (16 rows x K=128 fp4 = 16 B/lane) from LDS; conflict-free
#define READ_FRAG(base, rowbase, dst)                                          \
  {                                                                            \
    const i32x4 d_ = *(const i32x4*)(smem + (base) +                           \
                                     ((rowbase) + l15) * 64 + gcol);           \
    dst = (i32x8){d_[0], d_[1], d_[2], d_[3], 0, 0, 0, 0};                     \
  }

__global__ __launch_bounds__(256, 2)
void lse_gemm(const unsigned char* __restrict__ hf4,
              const unsigned char* __restrict__ wf4,
              const float* __restrict__ bias,
              float* __restrict__ ps) {
  // 3 bufs x (A 8K | B 8K) = 48K | red 128x2 f32 @49152
  __shared__ __align__(16) char smem[50176];

  const int bid = (int)blockIdx.x;
  const int logical = (bid & 7) * (NBLK / 8) + (bid >> 3);  // T1 XCD chunking
  const int colt = logical >> 4;           // 0..1023 (16 row-tiles share panel)
  const int m0 = (logical & 15) * BM;
  const int v0 = colt * BN;

  const int tid = threadIdx.x;
  const int lane = tid & 63;
  const int wv = tid >> 6, wm = wv >> 1, wn = wv & 1;   // 2x2 waves, 64x64 out
  const int l15 = lane & 15, l16g = lane >> 4;
  const int gcol = (l16g ^ ((l15 >> 1) & 3)) << 4;      // read-side swizzle

  // staging source: row r = tid>>2, slot g = tid&3 holds global granule
  // G = g ^ ((r>>1)&3) = (tid&3) ^ ((tid>>3)&3)  (row parity of j*64 is even)
  const int G_ = (tid & 3) ^ ((tid >> 3) & 3);
  const char* habase = (const char*)hf4 + (size_t)(m0 + (tid >> 2)) * 512 + G_ * 16;
  const char* wbase  = (const char*)wf4 + (size_t)(v0 + (tid >> 2)) * 512 + G_ * 16;

  f32x4 acc[4][4];
  const f32x4 zero = {0.f, 0.f, 0.f, 0.f};
#pragma unroll
  for (int i = 0; i < 4; ++i)
#pragma unroll
    for (int j = 0; j < 4; ++j) acc[i][j] = zero;

  i32x8 ar[2], breg[4];

  // ---- prologue: stage tile0 -> buf0, tile1 -> buf1 (8 loads in flight) ----
  STAGE(habase, 0, 0, 0);
  STAGE(wbase, 8192, 0, 0);
  STAGE(habase, 0, 1, 1);
  STAGE(wbase, 8192, 1, 1);
  SCHB();

  // ---- main loop: 1 K-tile/iter; counted vmcnt(4) + ONE barrier per iter ----
#pragma unroll
  for (int t = 0; t < K_TILES; ++t) {
    const int buf = t % 3;
    if (t < K_TILES - 1) { VM4(); } else { VM0(); }  // tile-t DMA landed
    BAR();               // tile-t visible to all waves; buf[(t+2)%3] free
    if (t < K_TILES - 2) {
      STAGE(habase, 0, t + 2, (t + 2) % 3);
      STAGE(wbase, 8192, t + 2, (t + 2) % 3);
      SCHB();
    }
    // ---- B-frags once into regs (x4 reuse) ----
#pragma unroll
    for (int q = 0; q < 4; ++q)
      READ_FRAG(buf * 16384 + 8192, wn * 64 + q * 16, breg[q]);
    // ---- stream 4 A-frags, 2-deep; 4 MFMAs per frag; fmt 4 = fp4 e2m1 ----
    READ_FRAG(buf * 16384, wm * 64, ar[0]);
#pragma unroll
    for (int f = 0; f < 4; ++f) {
      if (f < 3) READ_FRAG(buf * 16384, wm * 64 + (f + 1) * 16, ar[(f + 1) & 1]);
      SP1();
#pragma unroll
      for (int q = 0; q < 4; ++q)
        acc[f][q] = __builtin_amdgcn_mfma_scale_f32_16x16x128_f8f6f4(
            ar[f & 1], breg[q], acc[f][q], 4, 4, 0, SCL_A, 0, SCL_B);
      SP0();
    }
  }
  __syncthreads();

  // ---- epilogue: per-row sum(exp(x+bias)); shfl pre-reduce over 16 lanes ----
  float* red = (float*)(smem + 49152);     // [128][2] f32
  float bv[4];
#pragma unroll
  for (int q = 0; q < 4; ++q)
    bv[q] = bias[v0 + wn * 64 + q * 16 + l15];
#pragma unroll
  for (int mi = 0; mi < 4; ++mi) {
#pragma unroll
    for (int r = 0; r < 4; ++r) {
      float v = __expf(acc[mi][0][r] + bv[0]) + __expf(acc[mi][1][r] + bv[1]) +
                __expf(acc[mi][2][r] + bv[2]) + __expf(acc[mi][3][r] + bv[3]);
      v += __shfl_xor(v, 1); v += __shfl_xor(v, 2);
      v += __shfl_xor(v, 4); v += __shfl_xor(v, 8);
      if (l15 == 0) red[(wm * 64 + mi * 16 + l16g * 4 + r) * 2 + wn] = v;
    }
  }
  __syncthreads();
  if (tid < BM)
    ps[(size_t)(m0 + tid) * COL_TILES + colt] = red[tid * 2] + red[tid * 2 + 1];
}

// ---------------- per-row finalize: sum partials -> lse, target logit, ce ----
__global__ __launch_bounds__(256)
void row_finalize(const float* __restrict__ ps,
                  const float* __restrict__ hidden, const float* __restrict__ weight,
                  const float* __restrict__ bias, const int* __restrict__ labels,
                  float* __restrict__ ce) {
  __shared__ float ss[4], sd[4];
  const int row = blockIdx.x;
  const int t = threadIdx.x, lane = t & 63, w = t >> 6;

  float s = 0.f;
#pragma unroll
  for (int i = 0; i < COL_TILES / 256; ++i)
    s += ps[(size_t)row * COL_TILES + t + i * 256];

  const int lbl = labels[row];
  const bool valid = (lbl != IGNORE_INDEX);
  float dot = 0.f;
  if (valid) {
    const float4 h4 = *(const float4*)&hidden[(size_t)row * D_DIM + t * 4];
    const float4 w4 = *(const float4*)&weight[(size_t)lbl * D_DIM + t * 4];
    dot = h4.x * w4.x + h4.y * w4.y + h4.z * w4.z + h4.w * w4.w;
  }
#pragma unroll
  for (int msk = 1; msk < 64; msk <<= 1) {
    s += __shfl_xor(s, msk);
    dot += __shfl_xor(dot, msk);
  }
  if (lane == 0) { ss[w] = s; sd[w] = dot; }
  __syncthreads();
  if (t == 0) {
    const float S = ss[0] + ss[1] + ss[2] + ss[3];
    const float d = sd[0] + sd[1] + sd[2] + sd[3];
    ce[row] = valid ? (logf(S + 1e-10f) - (d + bias[lbl])) : 0.f;
  }
}

// ---------------- final scalar reduce ----------------
__global__ __launch_bounds__(256)
void final_reduce(const float* __restrict__ ce, const int* __restrict__ labels,
                  float* __restrict__ out) {
  __shared__ float ssum[4];
  __shared__ int scnt[4];
  const int t = threadIdx.x, lane = t & 63, w = t >> 6;
  float sum = 0.f; int cnt = 0;
  for (int i = t; i < N_ROWS; i += 256) {
    sum += ce[i];
    cnt += (labels[i] != IGNORE_INDEX) ? 1 : 0;
  }
#pragma unroll
  for (int msk = 1; msk < 64; msk <<= 1) {
    sum += __shfl_xor(sum, msk);
    cnt += __shfl_xor(cnt, msk);
  }
  if (lane == 0) { ssum[w] = sum; scnt[w] = cnt; }
  __syncthreads();
  if (t == 0) {
    const float S = ssum[0] + ssum[1] + ssum[2] + ssum[3];
    const int C = scnt[0] + scnt[1] + scnt[2] + scnt[3];
    out[0] = S / fmaxf((float)C, 1.f);
  }
}

extern "C" void kernel_launch(void* const* d_in, const int* in_sizes, int n_in,
                              void* d_out, int out_size, void* d_ws, size_t ws_size,
                              hipStream_t stream) {
  const float* hidden = (const float*)d_in[0];
  const float* weight = (const float*)d_in[1];
  const float* bias   = (const float*)d_in[2];
  const int*   labels = (const int*)d_in[3];
  float* out = (float*)d_out;

  const size_t WF4_B = (size_t)V_DIM * D_DIM / 2;          // 64 MB
  const size_t HF4_B = (size_t)N_ROWS * D_DIM / 2;         // 1 MB
  const size_t PS_B  = (size_t)N_ROWS * COL_TILES * 4;     // 8 MB
  const size_t CE_B  = (size_t)N_ROWS * 4;
  if (ws_size < WF4_B + HF4_B + PS_B + CE_B) return;

  char* ws = (char*)d_ws;
  unsigned char* wf4 = (unsigned char*)ws;
  unsigned char* hf4 = (unsigned char*)(ws + WF4_B);
  float* ps = (float*)(ws + WF4_B + HF4_B);
  float* ce = (float*)(ws + WF4_B + HF4_B + PS_B);

  cvt_fp4<<<(int)((size_t)V_DIM * D_DIM / 8192), 256, 0, stream>>>(weight, wf4, 64.0f);
  cvt_fp4<<<(int)((size_t)N_ROWS * D_DIM / 8192), 256, 0, stream>>>(hidden, hf4, 1.0f);
  lse_gemm<<<NBLK, 256, 0, stream>>>(hf4, wf4, bias, ps);
  row_finalize<<<N_ROWS, 256, 0, stream>>>(ps, hidden, weight, bias, labels, ce);
  final_reduce<<<1, 256, 0, stream>>>(ce, labels, out);
}

// Round 14
// 301.311 us; speedup vs baseline: 2.5562x; 1.5735x over previous
//
#include <hip/hip_runtime.h>

#define IGNORE_INDEX (-100)

constexpr int N_ROWS = 2048;
constexpr int D_DIM  = 1024;
constexpr int V_DIM  = 131072;
constexpr int BM = 256, BN = 256, BK = 128;
constexpr int ROW_TILES = N_ROWS / BM;        // 8
constexpr int COL_TILES = V_DIM / BN;         // 512
constexpr int NBLK = ROW_TILES * COL_TILES;   // 4096
constexpr int K_TILES = D_DIM / BK;           // 8
constexpr int GROUPS  = K_TILES / 2;          // 4 (2 K-tiles per sync group)

typedef __attribute__((ext_vector_type(4))) float f32x4;
typedef __attribute__((ext_vector_type(4))) int   i32x4;
typedef __attribute__((ext_vector_type(8))) int   i32x8;

// Uniform E8M0 scales: hidden at prescale 1 (2^0=127), weight at prescale 64
// (2^-6=121). Product 2^0 * 2^-6 * 64 = 1. Uniform bytes -> layout-proof.
#define SCL_A 0x7F7F7F7Fu
#define SCL_B 0x79797979u

// ---------------- f32 -> fp4 e2m1 (software RNE to grid), 32 elems/thread ----
__device__ __forceinline__ unsigned int f2fp4(float f) {
  const float a = fabsf(f);
  unsigned int c = (unsigned)(a >= 0.25f) + (unsigned)(a >= 0.75f) +
                   (unsigned)(a >= 1.25f) + (unsigned)(a >= 1.75f) +
                   (unsigned)(a >= 2.5f)  + (unsigned)(a >= 3.5f) +
                   (unsigned)(a >= 5.0f);
  return c | ((__float_as_uint(f) >> 31) << 3);
}

__global__ __launch_bounds__(256)
void cvt_fp4(const float* __restrict__ src, unsigned char* __restrict__ dst,
             float prescale) {
  const size_t i = ((size_t)blockIdx.x * 256 + (size_t)threadIdx.x) * 32;
  i32x4 o;
#pragma unroll
  for (int q = 0; q < 4; ++q) {        // 1 dword = 8 elems, low nibble first
    unsigned int wrd = 0;
#pragma unroll
    for (int e = 0; e < 8; e += 4) {
      const float4 f = *(const float4*)&src[i + q * 8 + e];
      wrd |= f2fp4(f.x * prescale) << ((e + 0) * 4);
      wrd |= f2fp4(f.y * prescale) << ((e + 1) * 4);
      wrd |= f2fp4(f.z * prescale) << ((e + 2) * 4);
      wrd |= f2fp4(f.w * prescale) << ((e + 3) * 4);
    }
    o[q] = (int)wrd;
  }
  *(i32x4*)&dst[i / 2] = o;
}

// ---------------- 256x256 MX-fp4 GEMM + partial row exp-sum ----------------
// Round-10 structure with 2-K-tile sync groups: ONE vmcnt-drain + ONE barrier
// per 2 K-tiles (dbuf 2x64KB). Halves the per-tile VM/BAR/read-latency stall
// that r10 paid 8x per block. All data paths byte-frozen from round-10.
#define BAR() __builtin_amdgcn_s_barrier()
#define SP1() __builtin_amdgcn_s_setprio(1)
#define SP0() __builtin_amdgcn_s_setprio(0)
#define SCHB() __builtin_amdgcn_sched_barrier(0)
#define VM0() asm volatile("s_waitcnt vmcnt(0)" ::: "memory")

// stage one 256x128-elem fp4 tile (16 KB) at dstoff: 2 x gload_lds(16B)/thread
#define STAGE_TILE(gbase, dstoff, kt)                                          \
  {                                                                            \
    _Pragma("unroll") for (int j_ = 0; j_ < 2; ++j_) {                         \
      const char* g_ = (gbase) + (size_t)j_ * 65536 + (size_t)(kt) * 64;       \
      __builtin_amdgcn_global_load_lds(                                        \
          (const __attribute__((address_space(1))) unsigned int*)g_,           \
          (__attribute__((address_space(3))) unsigned int*)(smem + (dstoff) +  \
              j_ * 8192 + (tid << 4)),                                         \
          16, 0, 0);                                                           \
    }                                                                          \
  }

// stage one group (K-tiles 2g, 2g+1; A + B) into buffer b
#define STAGE_GROUP(g, b)                                                      \
  {                                                                            \
    STAGE_TILE(habase, (b) * 65536 + 0,     2 * (g));                          \
    STAGE_TILE(habase, (b) * 65536 + 16384, 2 * (g) + 1);                      \
    STAGE_TILE(wbase,  (b) * 65536 + 32768, 2 * (g));                          \
    STAGE_TILE(wbase,  (b) * 65536 + 49152, 2 * (g) + 1);                      \
  }

// read ONE frag (16 rows x K=128 fp4 = 16 B/lane) from LDS; conflict-free
#define READ_FRAG(base, rowbase, dst)                                          \
  {                                                                            \
    const i32x4 d_ = *(const i32x4*)(smem + (base) +                           \
                                     ((rowbase) + l15) * 64 + gcol);           \
    dst = (i32x8){d_[0], d_[1], d_[2], d_[3], 0, 0, 0, 0};                     \
  }

__global__ __launch_bounds__(512, 1)
void lse_gemm(const unsigned char* __restrict__ hf4,
              const unsigned char* __restrict__ wf4,
              const float* __restrict__ bias,
              float* __restrict__ ps) {
  // dbuf x 64KB groups (A0,A1,B0,B1 16KB each); epilogue red overlays
  __shared__ __align__(16) char smem[131072];

  const int bid = (int)blockIdx.x;
  const int logical = (bid & 7) * (NBLK / 8) + (bid >> 3);  // T1 XCD chunking
  const int colt = logical >> 3;           // 0..511
  const int m0 = (logical & 7) * BM;
  const int v0 = colt * BN;

  const int tid = threadIdx.x;
  const int lane = tid & 63;
  const int wm = (tid >> 6) >> 2, wn = (tid >> 6) & 3;  // 2x4 waves, 128x64 out
  const int l15 = lane & 15, l16g = lane >> 4;
  const int gcol = (l16g ^ ((l15 >> 1) & 3)) << 4;      // read-side swizzle

  // staging source: row r = tid>>2, granule slot g = tid&3 holds global
  // granule G = g ^ ((r>>1)&3) (same involution as read side).
  const int r_ = tid >> 2, g_ = tid & 3;
  const int G_ = g_ ^ ((r_ >> 1) & 3);
  const char* habase = (const char*)hf4 + (size_t)(m0 + r_) * 512 + G_ * 16;
  const char* wbase  = (const char*)wf4 + (size_t)(v0 + r_) * 512 + G_ * 16;

  f32x4 acc[8][4];
  const f32x4 zero = {0.f, 0.f, 0.f, 0.f};
#pragma unroll
  for (int i = 0; i < 8; ++i)
#pragma unroll
    for (int j = 0; j < 4; ++j) acc[i][j] = zero;

  i32x8 ar[2], breg[4];

  // ---- prologue: stage group 0 -> buf0 (8 loads in flight) ----
  STAGE_GROUP(0, 0);
  SCHB();

  // ---- main loop: 2 K-tiles per iter; ONE vmcnt-drain + ONE barrier ----
#pragma unroll
  for (int g = 0; g < GROUPS; ++g) {
    const int buf = g & 1;
    VM0();               // drains exactly group-g's 8 loads (g+1 not issued)
    BAR();               // group-g visible to all waves; buf^1 readers done
    if (g < GROUPS - 1) {
      STAGE_GROUP(g + 1, buf ^ 1);
      SCHB();
    }
#pragma unroll
    for (int k2 = 0; k2 < 2; ++k2) {
      const int ab = buf * 65536 + k2 * 16384;          // A tile base
      const int bb = buf * 65536 + 32768 + k2 * 16384;  // B tile base
      // ---- B-frags once into regs (x8 reuse) ----
#pragma unroll
      for (int q = 0; q < 4; ++q)
        READ_FRAG(bb, wn * 64 + q * 16, breg[q]);
      // ---- stream 8 A-frags, 2-deep; 4 MFMAs per frag ----
      READ_FRAG(ab, wm * 128, ar[0]);
#pragma unroll
      for (int f = 0; f < 8; ++f) {
        if (f < 7) READ_FRAG(ab, wm * 128 + (f + 1) * 16, ar[(f + 1) & 1]);
        SP1();
#pragma unroll
        for (int q = 0; q < 4; ++q)
          acc[f][q] = __builtin_amdgcn_mfma_scale_f32_16x16x128_f8f6f4(
              ar[f & 1], breg[q], acc[f][q], 4, 4, 0, SCL_A, 0, SCL_B);
        SP0();
      }
    }
  }
  __syncthreads();

  // ---- epilogue: per-row sum(exp(x+bias)) over this tile's 256 cols ----
  float* red = (float*)smem;               // [256][68] f32 (pad)
  float bv[4];
#pragma unroll
  for (int q = 0; q < 4; ++q)
    bv[q] = bias[v0 + wn * 64 + q * 16 + l15];
#pragma unroll
  for (int mi = 0; mi < 8; ++mi) {
#pragma unroll
    for (int r = 0; r < 4; ++r) {
      const float v = __expf(acc[mi][0][r] + bv[0]) + __expf(acc[mi][1][r] + bv[1]) +
                      __expf(acc[mi][2][r] + bv[2]) + __expf(acc[mi][3][r] + bv[3]);
      const int row = wm * 128 + mi * 16 + l16g * 4 + r;
      red[row * 68 + wn * 16 + l15] = v;
    }
  }
  __syncthreads();
  {
    const int row = tid >> 1, h = tid & 1;
    const float* rr = &red[row * 68 + h * 32];
    f32x4 s4 = *(const f32x4*)rr;
#pragma unroll
    for (int i = 1; i < 8; ++i) s4 += *(const f32x4*)(rr + i * 4);
    float s = s4[0] + s4[1] + s4[2] + s4[3];
    s += __shfl_xor(s, 1);
    if (h == 0) ps[(size_t)(m0 + row) * COL_TILES + colt] = s;
  }
}

// ---------------- per-row finalize: sum partials -> lse, target logit, ce ----
__global__ __launch_bounds__(256)
void row_finalize(const float* __restrict__ ps,
                  const float* __restrict__ hidden, const float* __restrict__ weight,
                  const float* __restrict__ bias, const int* __restrict__ labels,
                  float* __restrict__ ce) {
  __shared__ float ss[4], sd[4];
  const int row = blockIdx.x;
  const int t = threadIdx.x, lane = t & 63, w = t >> 6;

  float s = 0.f;
#pragma unroll
  for (int i = 0; i < COL_TILES / 256; ++i)
    s += ps[(size_t)row * COL_TILES + t + i * 256];

  const int lbl = labels[row];
  const bool valid = (lbl != IGNORE_INDEX);
  float dot = 0.f;
  if (valid) {
    const float4 h4 = *(const float4*)&hidden[(size_t)row * D_DIM + t * 4];
    const float4 w4 = *(const float4*)&weight[(size_t)lbl * D_DIM + t * 4];
    dot = h4.x * w4.x + h4.y * w4.y + h4.z * w4.z + h4.w * w4.w;
  }
#pragma unroll
  for (int msk = 1; msk < 64; msk <<= 1) {
    s += __shfl_xor(s, msk);
    dot += __shfl_xor(dot, msk);
  }
  if (lane == 0) { ss[w] = s; sd[w] = dot; }
  __syncthreads();
  if (t == 0) {
    const float S = ss[0] + ss[1] + ss[2] + ss[3];
    const float d = sd[0] + sd[1] + sd[2] + sd[3];
    ce[row] = valid ? (logf(S + 1e-10f) - (d + bias[lbl])) : 0.f;
  }
}

// ---------------- final scalar reduce ----------------
__global__ __launch_bounds__(256)
void final_reduce(const float* __restrict__ ce, const int* __restrict__ labels,
                  float* __restrict__ out) {
  __shared__ float ssum[4];
  __shared__ int scnt[4];
  const int t = threadIdx.x, lane = t & 63, w = t >> 6;
  float sum = 0.f; int cnt = 0;
  for (int i = t; i < N_ROWS; i += 256) {
    sum += ce[i];
    cnt += (labels[i] != IGNORE_INDEX) ? 1 : 0;
  }
#pragma unroll
  for (int msk = 1; msk < 64; msk <<= 1) {
    sum += __shfl_xor(sum, msk);
    cnt += __shfl_xor(cnt, msk);
  }
  if (lane == 0) { ssum[w] = sum; scnt[w] = cnt; }
  __syncthreads();
  if (t == 0) {
    const float S = ssum[0] + ssum[1] + ssum[2] + ssum[3];
    const int C = scnt[0] + scnt[1] + scnt[2] + scnt[3];
    out[0] = S / fmaxf((float)C, 1.f);
  }
}

extern "C" void kernel_launch(void* const* d_in, const int* in_sizes, int n_in,
                              void* d_out, int out_size, void* d_ws, size_t ws_size,
                              hipStream_t stream) {
  const float* hidden = (const float*)d_in[0];
  const float* weight = (const float*)d_in[1];
  const float* bias   = (const float*)d_in[2];
  const int*   labels = (const int*)d_in[3];
  float* out = (float*)d_out;

  const size_t WF4_B = (size_t)V_DIM * D_DIM / 2;          // 64 MB
  const size_t HF4_B = (size_t)N_ROWS * D_DIM / 2;         // 1 MB
  const size_t PS_B  = (size_t)N_ROWS * COL_TILES * 4;     // 4 MB
  const size_t CE_B  = (size_t)N_ROWS * 4;
  if (ws_size < WF4_B + HF4_B + PS_B + CE_B) return;

  char* ws = (char*)d_ws;
  unsigned char* wf4 = (unsigned char*)ws;
  unsigned char* hf4 = (unsigned char*)(ws + WF4_B);
  float* ps = (float*)(ws + WF4_B + HF4_B);
  float* ce = (float*)(ws + WF4_B + HF4_B + PS_B);

  cvt_fp4<<<(int)((size_t)V_DIM * D_DIM / 8192), 256, 0, stream>>>(weight, wf4, 64.0f);
  cvt_fp4<<<(int)((size_t)N_ROWS * D_DIM / 8192), 256, 0, stream>>>(hidden, hf4, 1.0f);
  lse_gemm<<<NBLK, 512, 0, stream>>>(hf4, wf4, bias, ps);
  row_finalize<<<N_ROWS, 256, 0, stream>>>(ps, hidden, weight, bias, labels, ce);
  final_reduce<<<1, 256, 0, stream>>>(ce, labels, out);
}